// Round 1
// baseline (364.715 us; speedup 1.0000x reference)
//
#include <hip/hip_runtime.h>
#include <math.h>

// ---------------- fast transcendental helpers ----------------
#if __has_builtin(__builtin_amdgcn_exp2f)
#define EXP2F(x) __builtin_amdgcn_exp2f(x)
#else
#define EXP2F(x) exp2f(x)
#endif
#if __has_builtin(__builtin_amdgcn_logf)
#define LOG2F(x) __builtin_amdgcn_logf(x)
#else
#define LOG2F(x) log2f(x)
#endif
#if __has_builtin(__builtin_amdgcn_rcpf)
#define RCPF(x) __builtin_amdgcn_rcpf(x)
#else
#define RCPF(x) (1.0f / (x))
#endif

#define LOG2E 1.4426950408889634f

typedef __bf16 bf16x8 __attribute__((ext_vector_type(8)));
typedef float f32x4 __attribute__((ext_vector_type(4)));

__device__ __forceinline__ float silu_f(float v) {
    return v * RCPF(1.0f + EXP2F(-v * LOG2E));
}
__device__ __forceinline__ float softplus_f(float v) {
    return fmaxf(v, 0.0f) + log1pf(__expf(-fabsf(v)));
}

// quad_perm DPP add. 0xB1 = swap pairs, 0x4E = swap halves -> quad sum.
template <int CTRL>
__device__ __forceinline__ float dpp_add(float v) {
    int r = __builtin_amdgcn_update_dpp(0, __float_as_int(v), CTRL, 0xF, 0xF, true);
    return v + __int_as_float(r);
}

// bf16 round-to-nearest-even helpers
__device__ __forceinline__ unsigned short bf16_rne(float f) {
    unsigned int u = __float_as_uint(f);
    return (unsigned short)((u + 0x7FFFu + ((u >> 16) & 1u)) >> 16);
}
__device__ __forceinline__ unsigned short bf16_hi(float f, float& rem) {
    unsigned int u = __float_as_uint(f);
    unsigned int hb = (u + 0x7FFFu + ((u >> 16) & 1u)) >> 16;
    rem = f - __uint_as_float(hb << 16);
    return (unsigned short)hb;
}

// async global->LDS 16B (wave-uniform LDS base + lane*16)
__device__ __forceinline__ void async_g2l16(const void* g, void* l) {
    __builtin_amdgcn_global_load_lds(
        (const __attribute__((address_space(1))) unsigned int*)g,
        (__attribute__((address_space(3))) unsigned int*)l, 16, 0, 0);
}

// ---------------- merged conversion kernel ----------------
// Blocks [0,3072): bf16 round of x (hi only; A-side low term dropped)
// Blocks [3072,4224): transpose+split w_in  (768x1536 -> [1536][768] h+l)
// Blocks [4224,4800): transpose+split w_out (768x768  -> [768][768] h+l)
__global__ __launch_bounds__(256) void conv_all_k(
    const float* __restrict__ x,
    unsigned short* __restrict__ xh,
    const float* __restrict__ w_in,
    unsigned short* __restrict__ wih, unsigned short* __restrict__ wil,
    const float* __restrict__ w_out,
    unsigned short* __restrict__ woh, unsigned short* __restrict__ wol)
{
    const int bid = blockIdx.x;
    if (bid < 3072) {
        int i = bid * 256 + threadIdx.x;
        float4 v = ((const float4*)x)[i];
        ushort4 h;
        h.x = bf16_rne(v.x);
        h.y = bf16_rne(v.y);
        h.z = bf16_rne(v.z);
        h.w = bf16_rne(v.w);
        ((ushort4*)xh)[i] = h;
        return;
    }
    const float* W;
    unsigned short *Th, *Tl;
    int N, bx, by;
    if (bid < 4224) {
        int b2 = bid - 3072;
        W = w_in; Th = wih; Tl = wil; N = 1536;
        bx = b2 % 48; by = b2 / 48;
    } else {
        int b3 = bid - 4224;
        W = w_out; Th = woh; Tl = wol; N = 768;
        bx = b3 % 24; by = b3 / 24;
    }
    const int K = 768;
    __shared__ float tile[32][33];
    const int tx = threadIdx.x & 31, ty = threadIdx.x >> 5;
    const int n0 = bx * 32, k0 = by * 32;
#pragma unroll
    for (int r = 0; r < 4; ++r)
        tile[ty + r * 8][tx] = W[(size_t)(k0 + ty + r * 8) * N + n0 + tx];
    __syncthreads();
#pragma unroll
    for (int r = 0; r < 4; ++r) {
        float v = tile[tx][ty + r * 8];
        float rem;
        unsigned short h = bf16_hi(v, rem);
        size_t o = (size_t)(n0 + ty + r * 8) * K + k0 + tx;
        Th[o] = h;
        Tl[o] = bf16_rne(rem);
    }
}

// ---------------- 2-term split-bf16 MFMA GEMM ----------------
// C = epi( Ah[M,K] @ (Bh+Bl)^T[N,K] + bias ).  1D grid, by-major within bx
// (consecutive blocks share the B column-panel -> per-XCD L2 keeps B panel
// h+l plus 4 A row-panels resident; traffic ~4x lower than 2D round-robin).
// 3 staged matrices (Ah | Bh | Bl = 24 KB) -> 3 blocks/CU.
template <int EPI>
__global__ __launch_bounds__(256, 3) void mgemm_k(
    const unsigned short* __restrict__ Ah,
    const unsigned short* __restrict__ Bth, const unsigned short* __restrict__ Btl,
    const float* __restrict__ bias,
    float* __restrict__ C, int K, int ldc, int nby)
{
    __shared__ unsigned short smem[3 * 4096];  // Ah | Bh | Bl, 128x32 bf16 each

    const int t = threadIdx.x;
    const int wave = t >> 6, lane = t & 63;
    const int bx = blockIdx.x / nby, by = blockIdx.x % nby;
    const int bm = by * 128, bn = bx * 128;
    const int mw = (wave >> 1) * 64, nw = (wave & 1) * 64;

    // staging: wave0 -> Ah rows 0-63, wave1 -> Ah rows 64-127,
    //          wave2 -> Bh (8 insts), wave3 -> Bl (8 insts)
    const unsigned short* smat;
    int row0, ninst;
    char* lmat;
    if      (wave == 0) { smat = Ah;  row0 = bm;      ninst = 4; lmat = (char*)smem; }
    else if (wave == 1) { smat = Ah;  row0 = bm + 64; ninst = 4; lmat = (char*)smem + 4096; }
    else if (wave == 2) { smat = Bth; row0 = bn;      ninst = 8; lmat = (char*)(smem + 4096); }
    else                { smat = Btl; row0 = bn;      ninst = 8; lmat = (char*)(smem + 8192); }
    const int lr = lane >> 2;
    const int kq = (lane & 3) ^ ((lane >> 3) & 3);
    const unsigned short* gbase = smat + (size_t)(row0 + lr) * K + kq * 8;

    const int la = lane & 15, g4 = lane >> 4;
    const int fo = (g4 ^ ((la >> 1) & 3)) * 8;
    const int aoff = (mw + la) * 32 + fo;
    const int boff = (nw + la) * 32 + fo;
    const unsigned short* pAh = smem + aoff;
    const unsigned short* pBh = smem + 4096 + boff;
    const unsigned short* pBl = smem + 8192 + boff;

    f32x4 acc[4][4];
#pragma unroll
    for (int i = 0; i < 4; ++i)
#pragma unroll
        for (int j = 0; j < 4; ++j) acc[i][j] = (f32x4){0.f, 0.f, 0.f, 0.f};

    for (int k0 = 0; k0 < K; k0 += 32) {
        const unsigned short* g = gbase + k0;
        if (ninst == 4) {
#pragma unroll
            for (int j = 0; j < 4; ++j)
                async_g2l16(g + (size_t)j * 16 * K, lmat + j * 1024);
        } else {
#pragma unroll
            for (int j = 0; j < 8; ++j)
                async_g2l16(g + (size_t)j * 16 * K, lmat + j * 1024);
        }
        __syncthreads();

        bf16x8 fah[4], fbh[4], fbl[4];
#pragma unroll
        for (int i = 0; i < 4; ++i) {
            fah[i] = *(const bf16x8*)(pAh + i * 512);
            fbh[i] = *(const bf16x8*)(pBh + i * 512);
            fbl[i] = *(const bf16x8*)(pBl + i * 512);
        }
#pragma unroll
        for (int i = 0; i < 4; ++i)
#pragma unroll
            for (int j = 0; j < 4; ++j)
                acc[i][j] = __builtin_amdgcn_mfma_f32_16x16x32_bf16(fah[i], fbh[j], acc[i][j], 0, 0, 0);
#pragma unroll
        for (int i = 0; i < 4; ++i)
#pragma unroll
            for (int j = 0; j < 4; ++j)
                acc[i][j] = __builtin_amdgcn_mfma_f32_16x16x32_bf16(fah[i], fbl[j], acc[i][j], 0, 0, 0);
        __syncthreads();
    }

#pragma unroll
    for (int i = 0; i < 4; ++i) {
        int row = bm + mw + i * 16 + g4 * 4;
#pragma unroll
        for (int j = 0; j < 4; ++j) {
            int col = bn + nw + j * 16 + la;
            float bz = bias ? bias[col] : 0.0f;
#pragma unroll
            for (int r = 0; r < 4; ++r) {
                float v = acc[i][j][r] + bz;
                if (EPI == 1) v = silu_f(v);
                C[(size_t)(row + r) * ldc + col] = v;
            }
        }
    }
}

// ---------------- generic tiled fp32 GEMM (small GEMMs) ----------------
#define BM 64
#define BN 64
#define BK 16

template <int EPI>
__global__ __launch_bounds__(256) void gemm_k(
    const float* __restrict__ A, int lda,
    const float* __restrict__ W, int ldw,
    const float* __restrict__ bias,
    float* __restrict__ C, int ldc,
    int M, int N, int K)
{
    __shared__ float As[BK][BM + 8];
    __shared__ float Ws[BK][BN];

    const int t  = threadIdx.x;
    const int tx = t & 15;
    const int ty = t >> 4;
    const int bn = blockIdx.x * BN;
    const int bm = blockIdx.y * BM;

    const int am  = t >> 2;
    const int ak4 = (t & 3) * 4;
    const int wk  = t >> 4;
    const int wn4 = (t & 15) * 4;

    const bool wfull = (bn + BN <= N);

    float acc[4][4];
#pragma unroll
    for (int i = 0; i < 4; ++i)
#pragma unroll
        for (int j = 0; j < 4; ++j) acc[i][j] = 0.0f;

    for (int k0 = 0; k0 < K; k0 += BK) {
        float4 av = *(const float4*)&A[(size_t)(bm + am) * lda + k0 + ak4];
        float4 wv;
        if (wfull) {
            wv = *(const float4*)&W[(size_t)(k0 + wk) * ldw + bn + wn4];
        } else {
            float tmp[4];
#pragma unroll
            for (int j = 0; j < 4; ++j) {
                int col = bn + wn4 + j;
                tmp[j] = (col < N) ? W[(size_t)(k0 + wk) * ldw + col] : 0.0f;
            }
            wv = make_float4(tmp[0], tmp[1], tmp[2], tmp[3]);
        }
        __syncthreads();
        As[ak4 + 0][am] = av.x;
        As[ak4 + 1][am] = av.y;
        As[ak4 + 2][am] = av.z;
        As[ak4 + 3][am] = av.w;
        *(float4*)&Ws[wk][wn4] = wv;
        __syncthreads();
#pragma unroll
        for (int k = 0; k < BK; ++k) {
            float4 a4 = *(const float4*)&As[k][ty * 4];
            float4 w4 = *(const float4*)&Ws[k][tx * 4];
            float ar[4] = {a4.x, a4.y, a4.z, a4.w};
            float wr[4] = {w4.x, w4.y, w4.z, w4.w};
#pragma unroll
            for (int i = 0; i < 4; ++i)
#pragma unroll
                for (int j = 0; j < 4; ++j)
                    acc[i][j] = fmaf(ar[i], wr[j], acc[i][j]);
        }
    }

#pragma unroll
    for (int i = 0; i < 4; ++i) {
        int row = bm + ty * 4 + i;
#pragma unroll
        for (int j = 0; j < 4; ++j) {
            int col = bn + tx * 4 + j;
            if (col < N) {
                float v = acc[i][j];
                if (bias) v += bias[col];
                if (EPI == 1) v = silu_f(v);
                else if (EPI == 2) v = softplus_f(v);
                C[(size_t)row * ldc + col] = v;
            }
        }
    }
}

// ---------------- sequential fractal scan ----------------
// v2: 2 recurrence chains per thread (d, d+8) for in-stream ILP —
// one chain's issue fills the other's dependency stalls (in-order waves).
// Transcendentals cut 6 -> 4 per step: coef = fma(exp2(dt*-A*log2e),-.25,.25)
// precomputed by staging waves into LDS; ldiff tracked as LOG2(s2) reusing
// the RCP(den) product; earg folded: earg = (2cf+1)*ldiff + cf*lq.
#define L_LEN 1024
#define CH 16
#define NCH (L_LEN / CH)
#define CHP (CH + 4)
#define CSTR 264  /* coef l-stride (16*16 + 8 pad) -> 4-way-max bank spread */

// one recurrence step; returns y contribution (before n-reduction)
__device__ __forceinline__ float fstep(float cf, float xv,
                                       float B0v, float B1v,
                                       float C0v, float C1v,
                                       float& h0, float& h1,
                                       float& lq, float& ldf)
{
    float c2   = fmaf(2.0f, cf, 1.0f);
    float earg = fmaf(c2, ldf, cf * lq);   // == cf*(2*ldf+lq) + ldf
    float g    = EXP2F(earg);
    h0 = fmaf(h0, g, B0v * xv);
    h1 = fmaf(h1, g, B1v * xv);
    float q  = fmaf(h0, h0, fmaf(h1, h1, 1e-8f));
    lq = LOG2F(q);
    float q2  = q * q;                                          // Estrin [3/3] Pade
    float num = fmaf(q2, q + 378.0f,              fmaf(17325.0f, q, 135135.0f));
    float den = fmaf(q2, fmaf(28.0f, q, 3150.0f), fmaf(62370.0f, q, 135135.0f));
    float s2  = num * RCPF(den);
    ldf = LOG2F(s2);                       // == LOG2(num)-LOG2(den) to ~2^-22
    return s2 * fmaf(C0v, h0, C1v * h1);
}

__global__ __launch_bounds__(256) void scan_k(
    const float* __restrict__ xz,   // M x 1536 (silu applied to both halves)
    const float* __restrict__ dtg,  // M x 768
    const float* __restrict__ xp,   // M x 112 (cols 48..111 = B/C)
    const float* __restrict__ A_log,
    unsigned short* __restrict__ ybh)  // M x 768 bf16 of y*silu(z)
{
    __shared__ float xdt_t[2][16][CHP];
    __shared__ float B0s[2][16][CHP];
    __shared__ float B1s[2][16][CHP];
    __shared__ float C0s[2][16][CHP];
    __shared__ float C1s[2][16][CHP];
    __shared__ float ysp[2][CH][16][4];
    __shared__ float coefs[2 * CH * CSTR];   // [buf][l][d][n] f32, padded

    const int t  = threadIdx.x;
    const int b  = blockIdx.y;
    const int d0 = blockIdx.x * 16;
    const size_t rowbase = (size_t)b * L_LEN;
    const bool is_chain = (t < 128);

    // chain thread -> (n, two d slots)
    const int n   = t & 15;
    const int dl2 = (t >> 4) & 7;
    const int da  = dl2;
    const int db  = dl2 + 8;
    const int ng  = n >> 2;
    float h0a = 0.f, h1a = 0.f, lqa = 0.f, ldfa = 0.f;
    float h0b = 0.f, h1b = 0.f, lqb = 0.f, ldfb = 0.f;
    if (is_chain) {
        float phase = 6.283185307179586f * (float)n / 16.0f;
        h0a = 0.01f * cosf(phase);
        h1a = 0.01f * sinf(phase);
        lqa = LOG2F(fmaf(h0a, h0a, fmaf(h1a, h1a, 1e-8f)));
        h0b = h0a; h1b = h1a; lqb = lqa;
    }

    // staging threads
    const int t2 = t - 128;             // 0..127
    const int hl = (t2 >> 2) & 15;      // 0..15 (rows, for t2<64)
    const int hf = (t2 & 3) * 4;        // d offset
    float nal[16];
    if (!is_chain) {
#pragma unroll
        for (int j = 0; j < 16; ++j)
            nal[j] = -__expf(A_log[j]) * LOG2E;
    }

    auto stage = [&](int cc) {
        const int bi = cc & 1;
        if (t2 < 64) {
            size_t row = rowbase + cc * CH + hl;
            float4 rx = *(const float4*)&xz[row * 1536 + d0 + hf];
            float4 rd = *(const float4*)&dtg[row * 768 + d0 + hf];
            xdt_t[bi][hf + 0][hl] = rx.x * rd.x;
            xdt_t[bi][hf + 1][hl] = rx.y * rd.y;
            xdt_t[bi][hf + 2][hl] = rx.z * rd.z;
            xdt_t[bi][hf + 3][hl] = rx.w * rd.w;
            // coef = fma(exp2(dt * -A*log2e), -0.25, 0.25) for 4 d x 16 n
            const float dvv[4] = {rd.x, rd.y, rd.z, rd.w};
#pragma unroll
            for (int k = 0; k < 4; ++k) {
                float dv = dvv[k];
                float cf[16];
#pragma unroll
                for (int j = 0; j < 16; ++j)
                    cf[j] = fmaf(EXP2F(dv * nal[j]), -0.25f, 0.25f);
                float* cbase = &coefs[bi * (CH * CSTR) + hl * CSTR + (hf + k) * 16];
#pragma unroll
                for (int j4 = 0; j4 < 4; ++j4)
                    *(float4*)(cbase + j4 * 4) =
                        make_float4(cf[4 * j4], cf[4 * j4 + 1], cf[4 * j4 + 2], cf[4 * j4 + 3]);
            }
        }
#pragma unroll
        for (int i = 0; i < 2; ++i) {
            int idx = t2 + 128 * i;          // 0..255 -> 16 rows x 16 quads
            int lb = idx >> 4, j4 = (idx & 15) * 4;
            float4 rbc = *(const float4*)&xp[(rowbase + cc * CH + lb) * 112 + 48 + j4];
            if (j4 < 32) {
                int nn = j4 >> 1;
                B0s[bi][nn][lb]     = rbc.x;
                B1s[bi][nn][lb]     = rbc.y;
                B0s[bi][nn + 1][lb] = rbc.z;
                B1s[bi][nn + 1][lb] = rbc.w;
            } else {
                int nn = (j4 - 32) >> 1;
                C0s[bi][nn][lb]     = rbc.x;
                C1s[bi][nn][lb]     = rbc.y;
                C0s[bi][nn + 1][lb] = rbc.z;
                C1s[bi][nn + 1][lb] = rbc.w;
            }
        }
    };

    auto store_y = [&](int cs) {
        if (t2 >= 64) return;
        const int bi = cs & 1;
        size_t row = rowbase + cs * CH + hl;
        float4 zq = *(const float4*)&xz[row * 1536 + 768 + d0 + hf];
        float yr[4];
#pragma unroll
        for (int j = 0; j < 4; ++j) {
            float4 p = *(const float4*)&ysp[bi][hl][hf + j][0];
            yr[j] = (p.x + p.y) + (p.z + p.w);
        }
        ushort4 hh;
        hh.x = bf16_rne(yr[0] * zq.x);
        hh.y = bf16_rne(yr[1] * zq.y);
        hh.z = bf16_rne(yr[2] * zq.z);
        hh.w = bf16_rne(yr[3] * zq.w);
        *(ushort4*)&ybh[row * 768 + d0 + hf] = hh;
    };

    if (!is_chain) stage(0);
    __syncthreads();

    for (int c = 0; c < NCH; ++c) {
        if (is_chain) {
            const int bi = c & 1;
            const float* xa  = &xdt_t[bi][da][0];
            const float* xb  = &xdt_t[bi][db][0];
            const float* b0r = &B0s[bi][n][0];
            const float* b1r = &B1s[bi][n][0];
            const float* c0r = &C0s[bi][n][0];
            const float* c1r = &C1s[bi][n][0];
            const float* cfA = &coefs[bi * (CH * CSTR) + da * 16 + n];
            const float* cfB = &coefs[bi * (CH * CSTR) + db * 16 + n];

            float4 pxa = *(const float4*)(xa);
            float4 pxb = *(const float4*)(xb);
            float4 pb0 = *(const float4*)(b0r);
            float4 pb1 = *(const float4*)(b1r);
            float4 pc0 = *(const float4*)(c0r);
            float4 pc1 = *(const float4*)(c1r);
            float cA[4], cB[4];
#pragma unroll
            for (int u = 0; u < 4; ++u) {
                cA[u] = cfA[u * CSTR];
                cB[u] = cfB[u * CSTR];
            }

            for (int l4 = 0; l4 < CH; l4 += 4) {
                float4 cxa = pxa, cxb = pxb;
                float4 cb0 = pb0, cb1 = pb1, cc0 = pc0, cc1 = pc1;
                float kA[4], kB[4];
#pragma unroll
                for (int u = 0; u < 4; ++u) { kA[u] = cA[u]; kB[u] = cB[u]; }
                if (l4 + 4 < CH) {
                    pxa = *(const float4*)(xa  + l4 + 4);
                    pxb = *(const float4*)(xb  + l4 + 4);
                    pb0 = *(const float4*)(b0r + l4 + 4);
                    pb1 = *(const float4*)(b1r + l4 + 4);
                    pc0 = *(const float4*)(c0r + l4 + 4);
                    pc1 = *(const float4*)(c1r + l4 + 4);
#pragma unroll
                    for (int u = 0; u < 4; ++u) {
                        cA[u] = cfA[(l4 + 4 + u) * CSTR];
                        cB[u] = cfB[(l4 + 4 + u) * CSTR];
                    }
                }
                const float xva[4] = {cxa.x, cxa.y, cxa.z, cxa.w};
                const float xvb[4] = {cxb.x, cxb.y, cxb.z, cxb.w};
                const float B0v[4] = {cb0.x, cb0.y, cb0.z, cb0.w};
                const float B1v[4] = {cb1.x, cb1.y, cb1.z, cb1.w};
                const float C0v[4] = {cc0.x, cc0.y, cc0.z, cc0.w};
                const float C1v[4] = {cc1.x, cc1.y, cc1.z, cc1.w};

#pragma unroll
                for (int u = 0; u < 4; ++u) {
                    float yva = fstep(kA[u], xva[u], B0v[u], B1v[u], C0v[u], C1v[u],
                                      h0a, h1a, lqa, ldfa);
                    float yvb = fstep(kB[u], xvb[u], B0v[u], B1v[u], C0v[u], C1v[u],
                                      h0b, h1b, lqb, ldfb);
                    yva = dpp_add<0xB1>(yva);
                    yva = dpp_add<0x4E>(yva);
                    yvb = dpp_add<0xB1>(yvb);
                    yvb = dpp_add<0x4E>(yvb);
                    if ((n & 3) == 0) {
                        ysp[bi][l4 + u][da][ng] = yva;
                        ysp[bi][l4 + u][db][ng] = yvb;
                    }
                }
            }
        } else {
            if (c + 1 < NCH) stage(c + 1);
            if (c >= 1) store_y(c - 1);
        }
        __syncthreads();
    }
    if (!is_chain) store_y(NCH - 1);
}

// ---------------- launcher ----------------
extern "C" void kernel_launch(void* const* d_in, const int* in_sizes, int n_in,
                              void* d_out, int out_size, void* d_ws, size_t ws_size,
                              hipStream_t stream)
{
    const float* x     = (const float*)d_in[0];
    const float* w_in  = (const float*)d_in[1];
    const float* w_xp  = (const float*)d_in[2];
    const float* w_dt  = (const float*)d_in[3];
    const float* b_dt  = (const float*)d_in[4];
    const float* w_out = (const float*)d_in[5];
    const float* b_out = (const float*)d_in[6];
    const float* A_log = (const float*)d_in[7];
    float* out = (float*)d_out;

    const int M = 4096;
    float* xz  = (float*)d_ws;                           // M*1536
    float* xp  = xz + (size_t)M * 1536;                  // M*112
    float* dtb = xp + (size_t)M * 112;                   // M*768
    unsigned short* ah  = (unsigned short*)(dtb + (size_t)M * 768);  // M*768 (x bf16)
    unsigned short* ybh = ah + (size_t)M * 768;          // M*768 (scan out bf16)
    unsigned short* wh  = ybh + (size_t)M * 768;         // 1536*768
    unsigned short* wl  = wh + (size_t)1536 * 768;
    unsigned short* voh = wl + (size_t)1536 * 768;       // 768*768
    unsigned short* vol = voh + (size_t)768 * 768;

    dim3 blk(256);

    // 1) conversions: x -> bf16, weights -> transposed hi/lo
    conv_all_k<<<dim3(4800), blk, 0, stream>>>(x, ah, w_in, wh, wl, w_out, voh, vol);

    // 2) xz = silu(x @ in_proj_w)   (2-term split, L2-swizzled)
    mgemm_k<1><<<dim3(12 * 32), blk, 0, stream>>>(ah, wh, wl, (const float*)nullptr, xz, 768, 1536, 32);

    // 3) xp = x_in @ x_proj_w
    gemm_k<0><<<dim3(2, M / BM), blk, 0, stream>>>(
        xz, 1536, w_xp, 112, (const float*)nullptr, xp, 112, M, 112, 768);

    // 4) dt = softplus(xp[:, :48] @ dt_proj_w + b)
    gemm_k<2><<<dim3(768 / BN, M / BM), blk, 0, stream>>>(
        xp, 112, w_dt, 768, b_dt, dtb, 768, M, 768, 48);

    // 5) scan -> ybh = bf16(y_scan * silu(z))
    scan_k<<<dim3(48, 4), dim3(256), 0, stream>>>(xz, dtb, xp, A_log, ybh);

    // 6) out = yb @ out_proj_w + b_out
    mgemm_k<0><<<dim3(6 * 32), blk, 0, stream>>>(ybh, voh, vol, b_out, out, 768, 768, 32);
}

// Round 2
// 326.165 us; speedup vs baseline: 1.1182x; 1.1182x over previous
//
#include <hip/hip_runtime.h>
#include <math.h>

// ---------------- fast transcendental helpers ----------------
#if __has_builtin(__builtin_amdgcn_exp2f)
#define EXP2F(x) __builtin_amdgcn_exp2f(x)
#else
#define EXP2F(x) exp2f(x)
#endif
#if __has_builtin(__builtin_amdgcn_logf)
#define LOG2F(x) __builtin_amdgcn_logf(x)
#else
#define LOG2F(x) log2f(x)
#endif
#if __has_builtin(__builtin_amdgcn_rcpf)
#define RCPF(x) __builtin_amdgcn_rcpf(x)
#else
#define RCPF(x) (1.0f / (x))
#endif

#define LOG2E 1.4426950408889634f

typedef __bf16 bf16x8 __attribute__((ext_vector_type(8)));
typedef float f32x4 __attribute__((ext_vector_type(4)));

__device__ __forceinline__ float silu_f(float v) {
    return v * RCPF(1.0f + EXP2F(-v * LOG2E));
}
__device__ __forceinline__ float softplus_f(float v) {
    return fmaxf(v, 0.0f) + log1pf(__expf(-fabsf(v)));
}

// quad_perm DPP add. 0xB1 = swap pairs, 0x4E = swap halves -> quad sum.
template <int CTRL>
__device__ __forceinline__ float dpp_add(float v) {
    int r = __builtin_amdgcn_update_dpp(0, __float_as_int(v), CTRL, 0xF, 0xF, true);
    return v + __int_as_float(r);
}

// bf16 round-to-nearest-even helpers
__device__ __forceinline__ unsigned short bf16_rne(float f) {
    unsigned int u = __float_as_uint(f);
    return (unsigned short)((u + 0x7FFFu + ((u >> 16) & 1u)) >> 16);
}
__device__ __forceinline__ unsigned short bf16_hi(float f, float& rem) {
    unsigned int u = __float_as_uint(f);
    unsigned int hb = (u + 0x7FFFu + ((u >> 16) & 1u)) >> 16;
    rem = f - __uint_as_float(hb << 16);
    return (unsigned short)hb;
}

// async global->LDS 16B (wave-uniform LDS base + lane*16)
__device__ __forceinline__ void async_g2l16(const void* g, void* l) {
    __builtin_amdgcn_global_load_lds(
        (const __attribute__((address_space(1))) unsigned int*)g,
        (__attribute__((address_space(3))) unsigned int*)l, 16, 0, 0);
}

// ---------------- merged conversion kernel ----------------
// Blocks [0,3072): bf16 round of x (hi only; A-side low term dropped)
// Blocks [3072,4224): transpose+split w_in  (768x1536 -> [1536][768] h+l)
// Blocks [4224,4800): transpose+split w_out (768x768  -> [768][768] h+l)
__global__ __launch_bounds__(256) void conv_all_k(
    const float* __restrict__ x,
    unsigned short* __restrict__ xh,
    const float* __restrict__ w_in,
    unsigned short* __restrict__ wih, unsigned short* __restrict__ wil,
    const float* __restrict__ w_out,
    unsigned short* __restrict__ woh, unsigned short* __restrict__ wol)
{
    const int bid = blockIdx.x;
    if (bid < 3072) {
        int i = bid * 256 + threadIdx.x;
        float4 v = ((const float4*)x)[i];
        ushort4 h;
        h.x = bf16_rne(v.x);
        h.y = bf16_rne(v.y);
        h.z = bf16_rne(v.z);
        h.w = bf16_rne(v.w);
        ((ushort4*)xh)[i] = h;
        return;
    }
    const float* W;
    unsigned short *Th, *Tl;
    int N, bx, by;
    if (bid < 4224) {
        int b2 = bid - 3072;
        W = w_in; Th = wih; Tl = wil; N = 1536;
        bx = b2 % 48; by = b2 / 48;
    } else {
        int b3 = bid - 4224;
        W = w_out; Th = woh; Tl = wol; N = 768;
        bx = b3 % 24; by = b3 / 24;
    }
    const int K = 768;
    __shared__ float tile[32][33];
    const int tx = threadIdx.x & 31, ty = threadIdx.x >> 5;
    const int n0 = bx * 32, k0 = by * 32;
#pragma unroll
    for (int r = 0; r < 4; ++r)
        tile[ty + r * 8][tx] = W[(size_t)(k0 + ty + r * 8) * N + n0 + tx];
    __syncthreads();
#pragma unroll
    for (int r = 0; r < 4; ++r) {
        float v = tile[tx][ty + r * 8];
        float rem;
        unsigned short h = bf16_hi(v, rem);
        size_t o = (size_t)(n0 + ty + r * 8) * K + k0 + tx;
        Th[o] = h;
        Tl[o] = bf16_rne(rem);
    }
}

// ---------------- 2-term split-bf16 MFMA GEMM ----------------
// C = epi( Ah[M,K] @ (Bh+Bl)^T[N,K] + bias ).  1D grid, by-major within bx
// (consecutive blocks share the B column-panel -> per-XCD L2 keeps B panel
// h+l plus 4 A row-panels resident; traffic ~4x lower than 2D round-robin).
// 3 staged matrices (Ah | Bh | Bl = 24 KB) -> 3 blocks/CU.
template <int EPI>
__global__ __launch_bounds__(256, 3) void mgemm_k(
    const unsigned short* __restrict__ Ah,
    const unsigned short* __restrict__ Bth, const unsigned short* __restrict__ Btl,
    const float* __restrict__ bias,
    float* __restrict__ C, int K, int ldc, int nby)
{
    __shared__ unsigned short smem[3 * 4096];  // Ah | Bh | Bl, 128x32 bf16 each

    const int t = threadIdx.x;
    const int wave = t >> 6, lane = t & 63;
    const int bx = blockIdx.x / nby, by = blockIdx.x % nby;
    const int bm = by * 128, bn = bx * 128;
    const int mw = (wave >> 1) * 64, nw = (wave & 1) * 64;

    // staging: wave0 -> Ah rows 0-63, wave1 -> Ah rows 64-127,
    //          wave2 -> Bh (8 insts), wave3 -> Bl (8 insts)
    const unsigned short* smat;
    int row0, ninst;
    char* lmat;
    if      (wave == 0) { smat = Ah;  row0 = bm;      ninst = 4; lmat = (char*)smem; }
    else if (wave == 1) { smat = Ah;  row0 = bm + 64; ninst = 4; lmat = (char*)smem + 4096; }
    else if (wave == 2) { smat = Bth; row0 = bn;      ninst = 8; lmat = (char*)(smem + 4096); }
    else                { smat = Btl; row0 = bn;      ninst = 8; lmat = (char*)(smem + 8192); }
    const int lr = lane >> 2;
    const int kq = (lane & 3) ^ ((lane >> 3) & 3);
    const unsigned short* gbase = smat + (size_t)(row0 + lr) * K + kq * 8;

    const int la = lane & 15, g4 = lane >> 4;
    const int fo = (g4 ^ ((la >> 1) & 3)) * 8;
    const int aoff = (mw + la) * 32 + fo;
    const int boff = (nw + la) * 32 + fo;
    const unsigned short* pAh = smem + aoff;
    const unsigned short* pBh = smem + 4096 + boff;
    const unsigned short* pBl = smem + 8192 + boff;

    f32x4 acc[4][4];
#pragma unroll
    for (int i = 0; i < 4; ++i)
#pragma unroll
        for (int j = 0; j < 4; ++j) acc[i][j] = (f32x4){0.f, 0.f, 0.f, 0.f};

    for (int k0 = 0; k0 < K; k0 += 32) {
        const unsigned short* g = gbase + k0;
        if (ninst == 4) {
#pragma unroll
            for (int j = 0; j < 4; ++j)
                async_g2l16(g + (size_t)j * 16 * K, lmat + j * 1024);
        } else {
#pragma unroll
            for (int j = 0; j < 8; ++j)
                async_g2l16(g + (size_t)j * 16 * K, lmat + j * 1024);
        }
        __syncthreads();

        bf16x8 fah[4], fbh[4], fbl[4];
#pragma unroll
        for (int i = 0; i < 4; ++i) {
            fah[i] = *(const bf16x8*)(pAh + i * 512);
            fbh[i] = *(const bf16x8*)(pBh + i * 512);
            fbl[i] = *(const bf16x8*)(pBl + i * 512);
        }
#pragma unroll
        for (int i = 0; i < 4; ++i)
#pragma unroll
            for (int j = 0; j < 4; ++j)
                acc[i][j] = __builtin_amdgcn_mfma_f32_16x16x32_bf16(fah[i], fbh[j], acc[i][j], 0, 0, 0);
#pragma unroll
        for (int i = 0; i < 4; ++i)
#pragma unroll
            for (int j = 0; j < 4; ++j)
                acc[i][j] = __builtin_amdgcn_mfma_f32_16x16x32_bf16(fah[i], fbl[j], acc[i][j], 0, 0, 0);
        __syncthreads();
    }

#pragma unroll
    for (int i = 0; i < 4; ++i) {
        int row = bm + mw + i * 16 + g4 * 4;
#pragma unroll
        for (int j = 0; j < 4; ++j) {
            int col = bn + nw + j * 16 + la;
            float bz = bias ? bias[col] : 0.0f;
#pragma unroll
            for (int r = 0; r < 4; ++r) {
                float v = acc[i][j][r] + bz;
                if (EPI == 1) v = silu_f(v);
                C[(size_t)(row + r) * ldc + col] = v;
            }
        }
    }
}

// ---------------- generic tiled fp32 GEMM (small GEMMs) ----------------
#define BM 64
#define BN 64
#define BK 16

template <int EPI>
__global__ __launch_bounds__(256) void gemm_k(
    const float* __restrict__ A, int lda,
    const float* __restrict__ W, int ldw,
    const float* __restrict__ bias,
    float* __restrict__ C, int ldc,
    int M, int N, int K)
{
    __shared__ float As[BK][BM + 8];
    __shared__ float Ws[BK][BN];

    const int t  = threadIdx.x;
    const int tx = t & 15;
    const int ty = t >> 4;
    const int bn = blockIdx.x * BN;
    const int bm = blockIdx.y * BM;

    const int am  = t >> 2;
    const int ak4 = (t & 3) * 4;
    const int wk  = t >> 4;
    const int wn4 = (t & 15) * 4;

    const bool wfull = (bn + BN <= N);

    float acc[4][4];
#pragma unroll
    for (int i = 0; i < 4; ++i)
#pragma unroll
        for (int j = 0; j < 4; ++j) acc[i][j] = 0.0f;

    for (int k0 = 0; k0 < K; k0 += BK) {
        float4 av = *(const float4*)&A[(size_t)(bm + am) * lda + k0 + ak4];
        float4 wv;
        if (wfull) {
            wv = *(const float4*)&W[(size_t)(k0 + wk) * ldw + bn + wn4];
        } else {
            float tmp[4];
#pragma unroll
            for (int j = 0; j < 4; ++j) {
                int col = bn + wn4 + j;
                tmp[j] = (col < N) ? W[(size_t)(k0 + wk) * ldw + col] : 0.0f;
            }
            wv = make_float4(tmp[0], tmp[1], tmp[2], tmp[3]);
        }
        __syncthreads();
        As[ak4 + 0][am] = av.x;
        As[ak4 + 1][am] = av.y;
        As[ak4 + 2][am] = av.z;
        As[ak4 + 3][am] = av.w;
        *(float4*)&Ws[wk][wn4] = wv;
        __syncthreads();
#pragma unroll
        for (int k = 0; k < BK; ++k) {
            float4 a4 = *(const float4*)&As[k][ty * 4];
            float4 w4 = *(const float4*)&Ws[k][tx * 4];
            float ar[4] = {a4.x, a4.y, a4.z, a4.w};
            float wr[4] = {w4.x, w4.y, w4.z, w4.w};
#pragma unroll
            for (int i = 0; i < 4; ++i)
#pragma unroll
                for (int j = 0; j < 4; ++j)
                    acc[i][j] = fmaf(ar[i], wr[j], acc[i][j]);
        }
    }

#pragma unroll
    for (int i = 0; i < 4; ++i) {
        int row = bm + ty * 4 + i;
#pragma unroll
        for (int j = 0; j < 4; ++j) {
            int col = bn + tx * 4 + j;
            if (col < N) {
                float v = acc[i][j];
                if (bias) v += bias[col];
                if (EPI == 1) v = silu_f(v);
                else if (EPI == 2) v = softplus_f(v);
                C[(size_t)row * ldc + col] = v;
            }
        }
    }
}

// ---------------- sequential fractal scan (v1 structure + short-path math) --
// 1 chain/thread, 512 threads (4 chain waves + 4 staging waves per block).
// State (s2, lT) with lT = log2(tanh^2 m) = log2(s2^2 q):
//   g = s2 * exp2(cf * lT)     [== exp2(cf*(2*ldiff+lq) + ldiff)]
// Trans per step: exp2(alpha) [off-path], exp2(g), log2(T), rcp(den) = 4
// (was 6). cf and B*x hoisted to the per-l4-group operand block.
#define L_LEN 1024
#define CH 32
#define NCH (L_LEN / CH)
#define CHP (CH + 4)

__global__ __launch_bounds__(512) void scan_k(
    const float* __restrict__ xz,   // M x 1536 (silu applied to both halves)
    const float* __restrict__ dtg,  // M x 768
    const float* __restrict__ xp,   // M x 112 (cols 48..111 = B/C)
    const float* __restrict__ A_log,
    unsigned short* __restrict__ ybh)  // M x 768 bf16 of y*silu(z)
{
    __shared__ float xdt_t[2][16][CHP];
    __shared__ float ds_t[2][16][CHP];
    __shared__ float B0s[2][16][CHP];
    __shared__ float B1s[2][16][CHP];
    __shared__ float C0s[2][16][CHP];
    __shared__ float C1s[2][16][CHP];
    __shared__ float ysp[2][CH][16][4];

    const int t  = threadIdx.x;
    const int b  = blockIdx.y;
    const int d0 = blockIdx.x * 16;
    const size_t rowbase = (size_t)b * L_LEN;
    const bool is_chain = (t < 256);

    const int n  = t & 15;
    const int dl = (t >> 4) & 15;
    const int ng = n >> 2;
    float negAl2e = 0.0f, h0 = 0.0f, h1 = 0.0f;
    float s2 = 1.0f, lT = 0.0f;
    if (is_chain) {
        negAl2e = -__expf(A_log[n]) * LOG2E;
        float phase = 6.283185307179586f * (float)n / 16.0f;
        h0 = 0.01f * cosf(phase);
        h1 = 0.01f * sinf(phase);
        lT = LOG2F(fmaf(h0, h0, fmaf(h1, h1, 1e-8f)));   // s2=1 -> lT = lq0
    }

    const int t2 = t - 256;
    const int hl = t2 >> 2;
    const int hf = (t2 & 3) * 4;

    auto stage = [&](int cc) {
        const int bi = cc & 1;
        if (t2 < 128) {
            size_t row = rowbase + cc * CH + hl;
            float4 rx = *(const float4*)&xz[row * 1536 + d0 + hf];
            float4 rd = *(const float4*)&dtg[row * 768 + d0 + hf];
            xdt_t[bi][hf + 0][hl] = rx.x * rd.x;
            xdt_t[bi][hf + 1][hl] = rx.y * rd.y;
            xdt_t[bi][hf + 2][hl] = rx.z * rd.z;
            xdt_t[bi][hf + 3][hl] = rx.w * rd.w;
            ds_t[bi][hf + 0][hl] = rd.x;
            ds_t[bi][hf + 1][hl] = rd.y;
            ds_t[bi][hf + 2][hl] = rd.z;
            ds_t[bi][hf + 3][hl] = rd.w;
        }
#pragma unroll
        for (int i = 0; i < 2; ++i) {
            int idx = t2 + 256 * i;
            int lb = idx >> 4, j4 = (idx & 15) * 4;
            float4 rbc = *(const float4*)&xp[(rowbase + cc * CH + lb) * 112 + 48 + j4];
            if (j4 < 32) {
                int nn = j4 >> 1;
                B0s[bi][nn][lb]     = rbc.x;
                B1s[bi][nn][lb]     = rbc.y;
                B0s[bi][nn + 1][lb] = rbc.z;
                B1s[bi][nn + 1][lb] = rbc.w;
            } else {
                int nn = (j4 - 32) >> 1;
                C0s[bi][nn][lb]     = rbc.x;
                C1s[bi][nn][lb]     = rbc.y;
                C0s[bi][nn + 1][lb] = rbc.z;
                C1s[bi][nn + 1][lb] = rbc.w;
            }
        }
    };

    auto store_y = [&](int cs) {
        if (t2 >= 128) return;
        const int bi = cs & 1;
        size_t row = rowbase + cs * CH + hl;
        float4 zq = *(const float4*)&xz[row * 1536 + 768 + d0 + hf];
        float yr[4];
#pragma unroll
        for (int j = 0; j < 4; ++j) {
            float4 p = *(const float4*)&ysp[bi][hl][hf + j][0];
            yr[j] = (p.x + p.y) + (p.z + p.w);
        }
        ushort4 hh;
        hh.x = bf16_rne(yr[0] * zq.x);
        hh.y = bf16_rne(yr[1] * zq.y);
        hh.z = bf16_rne(yr[2] * zq.z);
        hh.w = bf16_rne(yr[3] * zq.w);
        *(ushort4*)&ybh[row * 768 + d0 + hf] = hh;
    };

    if (!is_chain) stage(0);
    __syncthreads();

    for (int c = 0; c < NCH; ++c) {
        if (is_chain) {
            const int bi = c & 1;
            const float* xr  = &xdt_t[bi][dl][0];
            const float* dr  = &ds_t[bi][dl][0];
            const float* b0r = &B0s[bi][n][0];
            const float* b1r = &B1s[bi][n][0];
            const float* c0r = &C0s[bi][n][0];
            const float* c1r = &C1s[bi][n][0];

            float4 px  = *(const float4*)(xr);
            float4 pd  = *(const float4*)(dr);
            float4 pb0 = *(const float4*)(b0r);
            float4 pb1 = *(const float4*)(b1r);
            float4 pc0 = *(const float4*)(c0r);
            float4 pc1 = *(const float4*)(c1r);

            for (int l4 = 0; l4 < CH; l4 += 4) {
                float4 cx = px, cd = pd, cb0 = pb0, cb1 = pb1, cc0 = pc0, cc1 = pc1;
                if (l4 + 4 < CH) {
                    px  = *(const float4*)(xr  + l4 + 4);
                    pd  = *(const float4*)(dr  + l4 + 4);
                    pb0 = *(const float4*)(b0r + l4 + 4);
                    pb1 = *(const float4*)(b1r + l4 + 4);
                    pc0 = *(const float4*)(c0r + l4 + 4);
                    pc1 = *(const float4*)(c1r + l4 + 4);
                }
                const float xv[4]  = {cx.x,  cx.y,  cx.z,  cx.w};
                const float dv[4]  = {cd.x,  cd.y,  cd.z,  cd.w};
                const float C0v[4] = {cc0.x, cc0.y, cc0.z, cc0.w};
                const float C1v[4] = {cc1.x, cc1.y, cc1.z, cc1.w};

                // off-path hoists: coefficient and B*x*dt for the 4 steps
                float cfv[4], bx0[4], bx1[4];
                const float B0v[4] = {cb0.x, cb0.y, cb0.z, cb0.w};
                const float B1v[4] = {cb1.x, cb1.y, cb1.z, cb1.w};
#pragma unroll
                for (int u = 0; u < 4; ++u) {
                    cfv[u] = fmaf(EXP2F(dv[u] * negAl2e), -0.25f, 0.25f);
                    bx0[u] = B0v[u] * xv[u];
                    bx1[u] = B1v[u] * xv[u];
                }

#pragma unroll
                for (int u = 0; u < 4; ++u) {
                    float g = s2 * EXP2F(cfv[u] * lT);
                    h0 = fmaf(h0, g, bx0[u]);
                    h1 = fmaf(h1, g, bx1[u]);
                    float q  = fmaf(h0, h0, fmaf(h1, h1, 1e-8f));
                    float q2 = q * q;                       // Estrin [3/3] Pade
                    float num = fmaf(q2, q + 378.0f,              fmaf(17325.0f, q, 135135.0f));
                    float den = fmaf(q2, fmaf(28.0f, q, 3150.0f), fmaf(62370.0f, q, 135135.0f));
                    s2 = num * RCPF(den);
                    lT = LOG2F(s2 * s2 * q);                // log2(tanh^2 m)

                    float yv = s2 * fmaf(C0v[u], h0, C1v[u] * h1);
                    yv = dpp_add<0xB1>(yv);
                    yv = dpp_add<0x4E>(yv);
                    if ((n & 3) == 0) ysp[bi][l4 + u][dl][ng] = yv;
                }
            }
        } else {
            if (c + 1 < NCH) stage(c + 1);
            if (c >= 1) store_y(c - 1);
        }
        __syncthreads();
    }
    if (!is_chain) store_y(NCH - 1);
}

// ---------------- launcher ----------------
extern "C" void kernel_launch(void* const* d_in, const int* in_sizes, int n_in,
                              void* d_out, int out_size, void* d_ws, size_t ws_size,
                              hipStream_t stream)
{
    const float* x     = (const float*)d_in[0];
    const float* w_in  = (const float*)d_in[1];
    const float* w_xp  = (const float*)d_in[2];
    const float* w_dt  = (const float*)d_in[3];
    const float* b_dt  = (const float*)d_in[4];
    const float* w_out = (const float*)d_in[5];
    const float* b_out = (const float*)d_in[6];
    const float* A_log = (const float*)d_in[7];
    float* out = (float*)d_out;

    const int M = 4096;
    float* xz  = (float*)d_ws;                           // M*1536
    float* xp  = xz + (size_t)M * 1536;                  // M*112
    float* dtb = xp + (size_t)M * 112;                   // M*768
    unsigned short* ah  = (unsigned short*)(dtb + (size_t)M * 768);  // M*768 (x bf16)
    unsigned short* ybh = ah + (size_t)M * 768;          // M*768 (scan out bf16)
    unsigned short* wh  = ybh + (size_t)M * 768;         // 1536*768
    unsigned short* wl  = wh + (size_t)1536 * 768;
    unsigned short* voh = wl + (size_t)1536 * 768;       // 768*768
    unsigned short* vol = voh + (size_t)768 * 768;

    dim3 blk(256);

    // 1) conversions: x -> bf16, weights -> transposed hi/lo
    conv_all_k<<<dim3(4800), blk, 0, stream>>>(x, ah, w_in, wh, wl, w_out, voh, vol);

    // 2) xz = silu(x @ in_proj_w)   (2-term split, L2-swizzled)
    mgemm_k<1><<<dim3(12 * 32), blk, 0, stream>>>(ah, wh, wl, (const float*)nullptr, xz, 768, 1536, 32);

    // 3) xp = x_in @ x_proj_w
    gemm_k<0><<<dim3(2, M / BM), blk, 0, stream>>>(
        xz, 1536, w_xp, 112, (const float*)nullptr, xp, 112, M, 112, 768);

    // 4) dt = softplus(xp[:, :48] @ dt_proj_w + b)
    gemm_k<2><<<dim3(768 / BN, M / BM), blk, 0, stream>>>(
        xp, 112, w_dt, 768, b_dt, dtb, 768, M, 768, 48);

    // 5) scan -> ybh = bf16(y_scan * silu(z))
    scan_k<<<dim3(48, 4), dim3(512), 0, stream>>>(xz, dtb, xp, A_log, ybh);

    // 6) out = yb @ out_proj_w + b_out
    mgemm_k<0><<<dim3(6 * 32), blk, 0, stream>>>(ybh, voh, vol, b_out, out, 768, 768, 32);
}

// Round 3
// 324.960 us; speedup vs baseline: 1.1223x; 1.0037x over previous
//
#include <hip/hip_runtime.h>
#include <math.h>

// ---------------- fast transcendental helpers ----------------
#if __has_builtin(__builtin_amdgcn_exp2f)
#define EXP2F(x) __builtin_amdgcn_exp2f(x)
#else
#define EXP2F(x) exp2f(x)
#endif
#if __has_builtin(__builtin_amdgcn_logf)
#define LOG2F(x) __builtin_amdgcn_logf(x)
#else
#define LOG2F(x) log2f(x)
#endif
#if __has_builtin(__builtin_amdgcn_rcpf)
#define RCPF(x) __builtin_amdgcn_rcpf(x)
#else
#define RCPF(x) (1.0f / (x))
#endif

#define LOG2E 1.4426950408889634f

typedef __bf16 bf16x8 __attribute__((ext_vector_type(8)));
typedef float f32x4 __attribute__((ext_vector_type(4)));

__device__ __forceinline__ float silu_f(float v) {
    return v * RCPF(1.0f + EXP2F(-v * LOG2E));
}
__device__ __forceinline__ float softplus_f(float v) {
    return fmaxf(v, 0.0f) + log1pf(__expf(-fabsf(v)));
}

// polynomial exp2: ~2e-8 rel err on f in [-0.5,0.5]; pure VALU (no trans pipe).
// valid for x in (-126, 127); our args are in [-40, 2].
__device__ __forceinline__ float exp2_fast(float x) {
    float r = __builtin_rintf(x);        // v_rndne_f32
    float f = x - r;
    int   n = (int)r;                    // v_cvt_i32_f32
    float p = 0.00133335581f;
    p = fmaf(p, f, 0.00961812910f);
    p = fmaf(p, f, 0.0555041087f);
    p = fmaf(p, f, 0.240226507f);
    p = fmaf(p, f, 0.69314718056f);
    p = fmaf(p, f, 1.0f);
    float sc = __int_as_float((n + 127) << 23);   // 2^n
    return p * sc;
}

// quad_perm DPP add. 0xB1 = swap pairs, 0x4E = swap halves -> quad sum.
template <int CTRL>
__device__ __forceinline__ float dpp_add(float v) {
    int r = __builtin_amdgcn_update_dpp(0, __float_as_int(v), CTRL, 0xF, 0xF, true);
    return v + __int_as_float(r);
}

// bf16 round-to-nearest-even helpers
__device__ __forceinline__ unsigned short bf16_rne(float f) {
    unsigned int u = __float_as_uint(f);
    return (unsigned short)((u + 0x7FFFu + ((u >> 16) & 1u)) >> 16);
}
__device__ __forceinline__ unsigned short bf16_hi(float f, float& rem) {
    unsigned int u = __float_as_uint(f);
    unsigned int hb = (u + 0x7FFFu + ((u >> 16) & 1u)) >> 16;
    rem = f - __uint_as_float(hb << 16);
    return (unsigned short)hb;
}

// async global->LDS 16B (wave-uniform LDS base + lane*16)
__device__ __forceinline__ void async_g2l16(const void* g, void* l) {
    __builtin_amdgcn_global_load_lds(
        (const __attribute__((address_space(1))) unsigned int*)g,
        (__attribute__((address_space(3))) unsigned int*)l, 16, 0, 0);
}

// ---------------- merged conversion kernel ----------------
// Blocks [0,3072): bf16 round of x (hi only; A-side low term dropped)
// Blocks [3072,4224): transpose+split w_in  (768x1536 -> [1536][768] h+l)
// Blocks [4224,4800): transpose+split w_out (768x768  -> [768][768] h+l)
__global__ __launch_bounds__(256) void conv_all_k(
    const float* __restrict__ x,
    unsigned short* __restrict__ xh,
    const float* __restrict__ w_in,
    unsigned short* __restrict__ wih, unsigned short* __restrict__ wil,
    const float* __restrict__ w_out,
    unsigned short* __restrict__ woh, unsigned short* __restrict__ wol)
{
    const int bid = blockIdx.x;
    if (bid < 3072) {
        int i = bid * 256 + threadIdx.x;
        float4 v = ((const float4*)x)[i];
        ushort4 h;
        h.x = bf16_rne(v.x);
        h.y = bf16_rne(v.y);
        h.z = bf16_rne(v.z);
        h.w = bf16_rne(v.w);
        ((ushort4*)xh)[i] = h;
        return;
    }
    const float* W;
    unsigned short *Th, *Tl;
    int N, bx, by;
    if (bid < 4224) {
        int b2 = bid - 3072;
        W = w_in; Th = wih; Tl = wil; N = 1536;
        bx = b2 % 48; by = b2 / 48;
    } else {
        int b3 = bid - 4224;
        W = w_out; Th = woh; Tl = wol; N = 768;
        bx = b3 % 24; by = b3 / 24;
    }
    const int K = 768;
    __shared__ float tile[32][33];
    const int tx = threadIdx.x & 31, ty = threadIdx.x >> 5;
    const int n0 = bx * 32, k0 = by * 32;
#pragma unroll
    for (int r = 0; r < 4; ++r)
        tile[ty + r * 8][tx] = W[(size_t)(k0 + ty + r * 8) * N + n0 + tx];
    __syncthreads();
#pragma unroll
    for (int r = 0; r < 4; ++r) {
        float v = tile[tx][ty + r * 8];
        float rem;
        unsigned short h = bf16_hi(v, rem);
        size_t o = (size_t)(n0 + ty + r * 8) * K + k0 + tx;
        Th[o] = h;
        Tl[o] = bf16_rne(rem);
    }
}

// ---------------- 2-term split-bf16 MFMA GEMM ----------------
// C = epi( Ah[M,K] @ (Bh+Bl)^T[N,K] + bias ).  1D grid, by-major within bx
// (consecutive blocks share the B column-panel -> per-XCD L2 keeps B panel
// h+l plus 4 A row-panels resident; traffic ~4x lower than 2D round-robin).
// 3 staged matrices (Ah | Bh | Bl = 24 KB) -> 3 blocks/CU.
template <int EPI>
__global__ __launch_bounds__(256, 3) void mgemm_k(
    const unsigned short* __restrict__ Ah,
    const unsigned short* __restrict__ Bth, const unsigned short* __restrict__ Btl,
    const float* __restrict__ bias,
    float* __restrict__ C, int K, int ldc, int nby)
{
    __shared__ unsigned short smem[3 * 4096];  // Ah | Bh | Bl, 128x32 bf16 each

    const int t = threadIdx.x;
    const int wave = t >> 6, lane = t & 63;
    const int bx = blockIdx.x / nby, by = blockIdx.x % nby;
    const int bm = by * 128, bn = bx * 128;
    const int mw = (wave >> 1) * 64, nw = (wave & 1) * 64;

    // staging: wave0 -> Ah rows 0-63, wave1 -> Ah rows 64-127,
    //          wave2 -> Bh (8 insts), wave3 -> Bl (8 insts)
    const unsigned short* smat;
    int row0, ninst;
    char* lmat;
    if      (wave == 0) { smat = Ah;  row0 = bm;      ninst = 4; lmat = (char*)smem; }
    else if (wave == 1) { smat = Ah;  row0 = bm + 64; ninst = 4; lmat = (char*)smem + 4096; }
    else if (wave == 2) { smat = Bth; row0 = bn;      ninst = 8; lmat = (char*)(smem + 4096); }
    else                { smat = Btl; row0 = bn;      ninst = 8; lmat = (char*)(smem + 8192); }
    const int lr = lane >> 2;
    const int kq = (lane & 3) ^ ((lane >> 3) & 3);
    const unsigned short* gbase = smat + (size_t)(row0 + lr) * K + kq * 8;

    const int la = lane & 15, g4 = lane >> 4;
    const int fo = (g4 ^ ((la >> 1) & 3)) * 8;
    const int aoff = (mw + la) * 32 + fo;
    const int boff = (nw + la) * 32 + fo;
    const unsigned short* pAh = smem + aoff;
    const unsigned short* pBh = smem + 4096 + boff;
    const unsigned short* pBl = smem + 8192 + boff;

    f32x4 acc[4][4];
#pragma unroll
    for (int i = 0; i < 4; ++i)
#pragma unroll
        for (int j = 0; j < 4; ++j) acc[i][j] = (f32x4){0.f, 0.f, 0.f, 0.f};

    for (int k0 = 0; k0 < K; k0 += 32) {
        const unsigned short* g = gbase + k0;
        if (ninst == 4) {
#pragma unroll
            for (int j = 0; j < 4; ++j)
                async_g2l16(g + (size_t)j * 16 * K, lmat + j * 1024);
        } else {
#pragma unroll
            for (int j = 0; j < 8; ++j)
                async_g2l16(g + (size_t)j * 16 * K, lmat + j * 1024);
        }
        __syncthreads();

        bf16x8 fah[4], fbh[4], fbl[4];
#pragma unroll
        for (int i = 0; i < 4; ++i) {
            fah[i] = *(const bf16x8*)(pAh + i * 512);
            fbh[i] = *(const bf16x8*)(pBh + i * 512);
            fbl[i] = *(const bf16x8*)(pBl + i * 512);
        }
#pragma unroll
        for (int i = 0; i < 4; ++i)
#pragma unroll
            for (int j = 0; j < 4; ++j)
                acc[i][j] = __builtin_amdgcn_mfma_f32_16x16x32_bf16(fah[i], fbh[j], acc[i][j], 0, 0, 0);
#pragma unroll
        for (int i = 0; i < 4; ++i)
#pragma unroll
            for (int j = 0; j < 4; ++j)
                acc[i][j] = __builtin_amdgcn_mfma_f32_16x16x32_bf16(fah[i], fbl[j], acc[i][j], 0, 0, 0);
        __syncthreads();
    }

#pragma unroll
    for (int i = 0; i < 4; ++i) {
        int row = bm + mw + i * 16 + g4 * 4;
#pragma unroll
        for (int j = 0; j < 4; ++j) {
            int col = bn + nw + j * 16 + la;
            float bz = bias ? bias[col] : 0.0f;
#pragma unroll
            for (int r = 0; r < 4; ++r) {
                float v = acc[i][j][r] + bz;
                if (EPI == 1) v = silu_f(v);
                C[(size_t)(row + r) * ldc + col] = v;
            }
        }
    }
}

// ---------------- generic tiled fp32 GEMM (small GEMMs) ----------------
#define BM 64
#define BN 64
#define BK 16

template <int EPI>
__global__ __launch_bounds__(256) void gemm_k(
    const float* __restrict__ A, int lda,
    const float* __restrict__ W, int ldw,
    const float* __restrict__ bias,
    float* __restrict__ C, int ldc,
    int M, int N, int K)
{
    __shared__ float As[BK][BM + 8];
    __shared__ float Ws[BK][BN];

    const int t  = threadIdx.x;
    const int tx = t & 15;
    const int ty = t >> 4;
    const int bn = blockIdx.x * BN;
    const int bm = blockIdx.y * BM;

    const int am  = t >> 2;
    const int ak4 = (t & 3) * 4;
    const int wk  = t >> 4;
    const int wn4 = (t & 15) * 4;

    const bool wfull = (bn + BN <= N);

    float acc[4][4];
#pragma unroll
    for (int i = 0; i < 4; ++i)
#pragma unroll
        for (int j = 0; j < 4; ++j) acc[i][j] = 0.0f;

    for (int k0 = 0; k0 < K; k0 += BK) {
        float4 av = *(const float4*)&A[(size_t)(bm + am) * lda + k0 + ak4];
        float4 wv;
        if (wfull) {
            wv = *(const float4*)&W[(size_t)(k0 + wk) * ldw + bn + wn4];
        } else {
            float tmp[4];
#pragma unroll
            for (int j = 0; j < 4; ++j) {
                int col = bn + wn4 + j;
                tmp[j] = (col < N) ? W[(size_t)(k0 + wk) * ldw + col] : 0.0f;
            }
            wv = make_float4(tmp[0], tmp[1], tmp[2], tmp[3]);
        }
        __syncthreads();
        As[ak4 + 0][am] = av.x;
        As[ak4 + 1][am] = av.y;
        As[ak4 + 2][am] = av.z;
        As[ak4 + 3][am] = av.w;
        *(float4*)&Ws[wk][wn4] = wv;
        __syncthreads();
#pragma unroll
        for (int k = 0; k < BK; ++k) {
            float4 a4 = *(const float4*)&As[k][ty * 4];
            float4 w4 = *(const float4*)&Ws[k][tx * 4];
            float ar[4] = {a4.x, a4.y, a4.z, a4.w};
            float wr[4] = {w4.x, w4.y, w4.z, w4.w};
#pragma unroll
            for (int i = 0; i < 4; ++i)
#pragma unroll
                for (int j = 0; j < 4; ++j)
                    acc[i][j] = fmaf(ar[i], wr[j], acc[i][j]);
        }
    }

#pragma unroll
    for (int i = 0; i < 4; ++i) {
        int row = bm + ty * 4 + i;
#pragma unroll
        for (int j = 0; j < 4; ++j) {
            int col = bn + tx * 4 + j;
            if (col < N) {
                float v = acc[i][j];
                if (bias) v += bias[col];
                if (EPI == 1) v = silu_f(v);
                else if (EPI == 2) v = softplus_f(v);
                C[(size_t)row * ldc + col] = v;
            }
        }
    }
}

// ---------------- sequential fractal scan (v4) ----------------
// Shell identical to the 117µs version. Chain body restructured:
//  - l4 loop FULLY unrolled (8 groups, compile-time), operand buffers
//    statically indexed [g&1] -> no float4 shadow copies, ds_read with
//    immediate offsets, counted lgkmcnt.
//  - manual polynomial exp2 on the recurrence path (no serial HW trans).
//  - parallel HW log2(q)/log2(num)/log2(den); rcp(den) only feeds y.
// State: (ldiff = log2 s2, lq = log2 q);  g = exp2(cf*(2*ldiff+lq) + ldiff).
#define L_LEN 1024
#define CH 32
#define NCH (L_LEN / CH)
#define CHP (CH + 4)

// one recurrence step; returns y contribution (before n-reduction)
__device__ __forceinline__ float fstep4(float cf, float bx0, float bx1,
                                        float C0v, float C1v,
                                        float& h0, float& h1,
                                        float& lq, float& ldf)
{
    float lg   = fmaf(2.0f, ldf, lq);
    float earg = fmaf(cf, lg, ldf);
    float g    = exp2_fast(earg);
    h0 = fmaf(h0, g, bx0);
    h1 = fmaf(h1, g, bx1);
    float q  = fmaf(h0, h0, fmaf(h1, h1, 1e-8f));
    float q2 = q * q;                                    // Estrin [3/3] Pade
    float num = fmaf(q2, q + 378.0f,              fmaf(17325.0f, q, 135135.0f));
    float den = fmaf(q2, fmaf(28.0f, q, 3150.0f), fmaf(62370.0f, q, 135135.0f));
    lq = LOG2F(q);                                       // 3 parallel HW logs
    float ln = LOG2F(num);
    float ld = LOG2F(den);
    ldf = ln - ld;                                       // log2(s2)
    float s2 = num * RCPF(den);                          // off-path (y only)
    return s2 * fmaf(C0v, h0, C1v * h1);
}

__global__ __launch_bounds__(512) void scan_k(
    const float* __restrict__ xz,   // M x 1536 (silu applied to both halves)
    const float* __restrict__ dtg,  // M x 768
    const float* __restrict__ xp,   // M x 112 (cols 48..111 = B/C)
    const float* __restrict__ A_log,
    unsigned short* __restrict__ ybh)  // M x 768 bf16 of y*silu(z)
{
    __shared__ float xdt_t[2][16][CHP];
    __shared__ float ds_t[2][16][CHP];
    __shared__ float B0s[2][16][CHP];
    __shared__ float B1s[2][16][CHP];
    __shared__ float C0s[2][16][CHP];
    __shared__ float C1s[2][16][CHP];
    __shared__ float ysp[2][CH][16][4];

    const int t  = threadIdx.x;
    const int b  = blockIdx.y;
    const int d0 = blockIdx.x * 16;
    const size_t rowbase = (size_t)b * L_LEN;
    const bool is_chain = (t < 256);

    const int n  = t & 15;
    const int dl = (t >> 4) & 15;
    const int ng = n >> 2;
    float negAl2e = 0.0f, h0 = 0.0f, h1 = 0.0f;
    float lq = 0.0f, ldf = 0.0f;
    if (is_chain) {
        negAl2e = -__expf(A_log[n]) * LOG2E;
        float phase = 6.283185307179586f * (float)n / 16.0f;
        h0 = 0.01f * cosf(phase);
        h1 = 0.01f * sinf(phase);
        lq = LOG2F(fmaf(h0, h0, fmaf(h1, h1, 1e-8f)));
    }

    const int t2 = t - 256;
    const int hl = t2 >> 2;
    const int hf = (t2 & 3) * 4;

    auto stage = [&](int cc) {
        const int bi = cc & 1;
        if (t2 < 128) {
            size_t row = rowbase + cc * CH + hl;
            float4 rx = *(const float4*)&xz[row * 1536 + d0 + hf];
            float4 rd = *(const float4*)&dtg[row * 768 + d0 + hf];
            xdt_t[bi][hf + 0][hl] = rx.x * rd.x;
            xdt_t[bi][hf + 1][hl] = rx.y * rd.y;
            xdt_t[bi][hf + 2][hl] = rx.z * rd.z;
            xdt_t[bi][hf + 3][hl] = rx.w * rd.w;
            ds_t[bi][hf + 0][hl] = rd.x;
            ds_t[bi][hf + 1][hl] = rd.y;
            ds_t[bi][hf + 2][hl] = rd.z;
            ds_t[bi][hf + 3][hl] = rd.w;
        }
#pragma unroll
        for (int i = 0; i < 2; ++i) {
            int idx = t2 + 256 * i;
            int lb = idx >> 4, j4 = (idx & 15) * 4;
            float4 rbc = *(const float4*)&xp[(rowbase + cc * CH + lb) * 112 + 48 + j4];
            if (j4 < 32) {
                int nn = j4 >> 1;
                B0s[bi][nn][lb]     = rbc.x;
                B1s[bi][nn][lb]     = rbc.y;
                B0s[bi][nn + 1][lb] = rbc.z;
                B1s[bi][nn + 1][lb] = rbc.w;
            } else {
                int nn = (j4 - 32) >> 1;
                C0s[bi][nn][lb]     = rbc.x;
                C1s[bi][nn][lb]     = rbc.y;
                C0s[bi][nn + 1][lb] = rbc.z;
                C1s[bi][nn + 1][lb] = rbc.w;
            }
        }
    };

    auto store_y = [&](int cs) {
        if (t2 >= 128) return;
        const int bi = cs & 1;
        size_t row = rowbase + cs * CH + hl;
        float4 zq = *(const float4*)&xz[row * 1536 + 768 + d0 + hf];
        float yr[4];
#pragma unroll
        for (int j = 0; j < 4; ++j) {
            float4 p = *(const float4*)&ysp[bi][hl][hf + j][0];
            yr[j] = (p.x + p.y) + (p.z + p.w);
        }
        ushort4 hh;
        hh.x = bf16_rne(yr[0] * zq.x);
        hh.y = bf16_rne(yr[1] * zq.y);
        hh.z = bf16_rne(yr[2] * zq.z);
        hh.w = bf16_rne(yr[3] * zq.w);
        *(ushort4*)&ybh[row * 768 + d0 + hf] = hh;
    };

    if (!is_chain) stage(0);
    __syncthreads();

    for (int c = 0; c < NCH; ++c) {
        if (is_chain) {
            const int bi = c & 1;
            const float* xr  = &xdt_t[bi][dl][0];
            const float* dr  = &ds_t[bi][dl][0];
            const float* b0r = &B0s[bi][n][0];
            const float* b1r = &B1s[bi][n][0];
            const float* c0r = &C0s[bi][n][0];
            const float* c1r = &C1s[bi][n][0];

            // double-buffered register operand groups, statically indexed
            float4 gx[2], gd[2], gb0[2], gb1[2], gc0[2], gc1[2];
            gx[0]  = *(const float4*)(xr);
            gd[0]  = *(const float4*)(dr);
            gb0[0] = *(const float4*)(b0r);
            gb1[0] = *(const float4*)(b1r);
            gc0[0] = *(const float4*)(c0r);
            gc1[0] = *(const float4*)(c1r);

#pragma unroll
            for (int g = 0; g < 8; ++g) {
                const int cur = g & 1, nxt = cur ^ 1;
                if (g < 7) {
                    const int o = 4 * (g + 1);
                    gx[nxt]  = *(const float4*)(xr  + o);
                    gd[nxt]  = *(const float4*)(dr  + o);
                    gb0[nxt] = *(const float4*)(b0r + o);
                    gb1[nxt] = *(const float4*)(b1r + o);
                    gc0[nxt] = *(const float4*)(c0r + o);
                    gc1[nxt] = *(const float4*)(c1r + o);
                }
                const float xv[4]  = {gx[cur].x,  gx[cur].y,  gx[cur].z,  gx[cur].w};
                const float dv[4]  = {gd[cur].x,  gd[cur].y,  gd[cur].z,  gd[cur].w};
                const float B0v[4] = {gb0[cur].x, gb0[cur].y, gb0[cur].z, gb0[cur].w};
                const float B1v[4] = {gb1[cur].x, gb1[cur].y, gb1[cur].z, gb1[cur].w};
                const float C0v[4] = {gc0[cur].x, gc0[cur].y, gc0[cur].z, gc0[cur].w};
                const float C1v[4] = {gc1[cur].x, gc1[cur].y, gc1[cur].z, gc1[cur].w};

                // off-path hoists: coefficient and B*x*dt for the 4 steps
                float cfv[4], bx0[4], bx1[4];
#pragma unroll
                for (int u = 0; u < 4; ++u) {
                    cfv[u] = fmaf(EXP2F(dv[u] * negAl2e), -0.25f, 0.25f);
                    bx0[u] = B0v[u] * xv[u];
                    bx1[u] = B1v[u] * xv[u];
                }

#pragma unroll
                for (int u = 0; u < 4; ++u) {
                    float yv = fstep4(cfv[u], bx0[u], bx1[u], C0v[u], C1v[u],
                                      h0, h1, lq, ldf);
                    yv = dpp_add<0xB1>(yv);
                    yv = dpp_add<0x4E>(yv);
                    if ((n & 3) == 0) ysp[bi][4 * g + u][dl][ng] = yv;
                }
            }
        } else {
            if (c + 1 < NCH) stage(c + 1);
            if (c >= 1) store_y(c - 1);
        }
        __syncthreads();
    }
    if (!is_chain) store_y(NCH - 1);
}

// ---------------- launcher ----------------
extern "C" void kernel_launch(void* const* d_in, const int* in_sizes, int n_in,
                              void* d_out, int out_size, void* d_ws, size_t ws_size,
                              hipStream_t stream)
{
    const float* x     = (const float*)d_in[0];
    const float* w_in  = (const float*)d_in[1];
    const float* w_xp  = (const float*)d_in[2];
    const float* w_dt  = (const float*)d_in[3];
    const float* b_dt  = (const float*)d_in[4];
    const float* w_out = (const float*)d_in[5];
    const float* b_out = (const float*)d_in[6];
    const float* A_log = (const float*)d_in[7];
    float* out = (float*)d_out;

    const int M = 4096;
    float* xz  = (float*)d_ws;                           // M*1536
    float* xp  = xz + (size_t)M * 1536;                  // M*112
    float* dtb = xp + (size_t)M * 112;                   // M*768
    unsigned short* ah  = (unsigned short*)(dtb + (size_t)M * 768);  // M*768 (x bf16)
    unsigned short* ybh = ah + (size_t)M * 768;          // M*768 (scan out bf16)
    unsigned short* wh  = ybh + (size_t)M * 768;         // 1536*768
    unsigned short* wl  = wh + (size_t)1536 * 768;
    unsigned short* voh = wl + (size_t)1536 * 768;       // 768*768
    unsigned short* vol = voh + (size_t)768 * 768;

    dim3 blk(256);

    // 1) conversions: x -> bf16, weights -> transposed hi/lo
    conv_all_k<<<dim3(4800), blk, 0, stream>>>(x, ah, w_in, wh, wl, w_out, voh, vol);

    // 2) xz = silu(x @ in_proj_w)   (2-term split, L2-swizzled)
    mgemm_k<1><<<dim3(12 * 32), blk, 0, stream>>>(ah, wh, wl, (const float*)nullptr, xz, 768, 1536, 32);

    // 3) xp = x_in @ x_proj_w
    gemm_k<0><<<dim3(2, M / BM), blk, 0, stream>>>(
        xz, 1536, w_xp, 112, (const float*)nullptr, xp, 112, M, 112, 768);

    // 4) dt = softplus(xp[:, :48] @ dt_proj_w + b)
    gemm_k<2><<<dim3(768 / BN, M / BM), blk, 0, stream>>>(
        xp, 112, w_dt, 768, b_dt, dtb, 768, M, 768, 48);

    // 5) scan -> ybh = bf16(y_scan * silu(z))
    scan_k<<<dim3(48, 4), dim3(512), 0, stream>>>(xz, dtb, xp, A_log, ybh);

    // 6) out = yb @ out_proj_w + b_out
    mgemm_k<0><<<dim3(6 * 32), blk, 0, stream>>>(ybh, voh, vol, b_out, out, 768, 768, 32);
}